// Round 4
// baseline (664.829 us; speedup 1.0000x reference)
//
#include <hip/hip_runtime.h>
#include <hip/hip_bf16.h>

#define B_    16
#define C_    128
#define TWOC  256
#define OUT_  128
#define HW    16384
#define WDIM  128
#define HDIM  128
#define KTOT  1152

typedef __attribute__((ext_vector_type(8))) short short8;
typedef __attribute__((ext_vector_type(4))) float floatx4;

__device__ __forceinline__ ushort f2bf(float f) {
    union { float f; uint u; } x; x.f = f;
    uint r = (x.u + 0x7FFFu + ((x.u >> 16) & 1u)) >> 16;   // RNE
    return (ushort)r;
}
__device__ __forceinline__ float bf2f(ushort u) {
    union { float f; uint u; } x; x.u = ((uint)u) << 16;
    return x.f;
}
// HW packed f32->bf16 (RNE, identical to f2bf on finite values), 1 instr per pair
__device__ __forceinline__ uint cvt_pk_bf16(float lo, float hi) {
    uint r;
    asm("v_cvt_pk_bf16_f32 %0, %1, %2" : "=v"(r) : "v"(lo), "v"(hi));
    return r;
}

// ---------------------------------------------------------------------------
// prep: en_w fp32 -> bf16 (once) + zero pooled accumulator
// ---------------------------------------------------------------------------
__global__ __launch_bounds__(256) void prep_kernel(
    const float* __restrict__ en_w, ushort* __restrict__ en_w_bf,
    float* __restrict__ pooled)
{
    int i = blockIdx.x * 256 + threadIdx.x;    // 0..32767
    en_w_bf[i] = f2bf(en_w[i]);
    if (i < B_ * TWOC) pooled[i] = 0.f;
}

// ---------------------------------------------------------------------------
// Kernel 1 (fused): enhance = relu(BN(concat @ en_w^T)) -> enh bf16 NHWC
//                   + global-average-pool partial sums -> atomicAdd(pooled)
//   Per block: one image row (128 px) of one b. K=256 in 8 chunks of 32.
//   chunk-ahead software pipeline; pre-converted bf16 weights; HW packed
//   converts; pool reduce folded into the main-loop barriers.
// ---------------------------------------------------------------------------
__global__ __launch_bounds__(256) void enhance_kernel(
    const float* __restrict__ ir, const float* __restrict__ vi,
    const ushort* __restrict__ en_w_bf,
    const float* __restrict__ gamma, const float* __restrict__ beta,
    const float* __restrict__ mean, const float* __restrict__ var,
    ushort* __restrict__ enh, float* __restrict__ pooled)
{
    __shared__ ushort Xs[128][40];   // pad 32->40 shorts
    __shared__ float red[256];
    const int b = blockIdx.y;
    const int p0 = blockIdx.x * 128;
    const int t = threadIdx.x;
    const int lane = t & 63, wave = t >> 6;
    const int wr = wave >> 1, wc = wave & 1;
    const int lr = lane & 15, kg = lane >> 4;
    const int px = t & 127, half = t >> 7;
    const int pc = t & 31, grp = t >> 5;

    floatx4 acc[4][4] = {};
    float fcur[16], fnxt[16];
    short8 a_cur[4], a_nxt[4];

    // prologue: input chunk 0 + weight chunk 0 (only exposed latency)
    {
        const float* src = ir + ((size_t)b * C_ + half * 16) * HW + p0 + px;
        #pragma unroll
        for (int jj = 0; jj < 16; ++jj) fcur[jj] = src[(size_t)jj * HW];
        #pragma unroll
        for (int i2 = 0; i2 < 4; ++i2) {
            int co = wr * 64 + i2 * 16 + lr;
            a_cur[i2] = *(const short8*)&en_w_bf[(size_t)co * TWOC + kg * 8];
        }
    }

    #pragma unroll
    for (int kc = 0; kc < 8; ++kc) {
        __syncthreads();     // (a) Xs reads of kc-1 done  (b) red[] of kc-1 complete
        {   // pack + stage chunk kc
            uint u[8];
            #pragma unroll
            for (int jj = 0; jj < 8; ++jj)
                u[jj] = cvt_pk_bf16(fcur[2 * jj], fcur[2 * jj + 1]);
            uint4* dst = (uint4*)&Xs[px][half * 16];
            dst[0] = make_uint4(u[0], u[1], u[2], u[3]);
            dst[1] = make_uint4(u[4], u[5], u[6], u[7]);
        }
        if (kc > 0 && t < 32) {   // pool finalize for chunk kc-1 (reads red)
            float s = red[t] + red[32 + t] + red[64 + t] + red[96 + t]
                    + red[128 + t] + red[160 + t] + red[192 + t] + red[224 + t];
            atomicAdd(&pooled[b * TWOC + (kc - 1) * 32 + t], s);
        }
        __syncthreads();     // Xs visible

        // prefetch chunk kc+1 (input + weights) — hidden under MFMA phase below
        if (kc < 7) {
            int c2b = (kc + 1) * 32 + half * 16;
            const float* src = (c2b < C_)
                ? ir + ((size_t)b * C_ + c2b) * HW + p0 + px
                : vi + ((size_t)b * C_ + (c2b - C_)) * HW + p0 + px;
            #pragma unroll
            for (int jj = 0; jj < 16; ++jj) fnxt[jj] = src[(size_t)jj * HW];
            #pragma unroll
            for (int i2 = 0; i2 < 4; ++i2) {
                int co = wr * 64 + i2 * 16 + lr;
                a_nxt[i2] = *(const short8*)&en_w_bf[(size_t)co * TWOC + (kc + 1) * 32 + kg * 8];
            }
        }

        // MFMA phase
        short8 bfr[4];
        #pragma unroll
        for (int j = 0; j < 4; ++j) {
            int pl = wc * 64 + j * 16 + lr;
            bfr[j] = *(const short8*)&Xs[pl][kg * 8];
        }
        #pragma unroll
        for (int i2 = 0; i2 < 4; ++i2)
            #pragma unroll
            for (int j = 0; j < 4; ++j)
                acc[i2][j] = __builtin_amdgcn_mfma_f32_16x16x32_bf16(a_cur[i2], bfr[j], acc[i2][j], 0, 0, 0);

        // pool partial: thread t sums channel (kc*32 + pc) over 16 pixels
        {
            float s = 0.f;
            #pragma unroll
            for (int q = 0; q < 16; ++q) s += bf2f(Xs[grp * 16 + q][pc]);
            red[t] = s;
        }

        if (kc < 7) {
            #pragma unroll
            for (int jj = 0; jj < 16; ++jj) fcur[jj] = fnxt[jj];
            #pragma unroll
            for (int i2 = 0; i2 < 4; ++i2) a_cur[i2] = a_nxt[i2];
        }
    }

    __syncthreads();
    if (t < 32) {   // pool finalize for chunk 7
        float s = red[t] + red[32 + t] + red[64 + t] + red[96 + t]
                + red[128 + t] + red[160 + t] + red[192 + t] + red[224 + t];
        atomicAdd(&pooled[b * TWOC + 7 * 32 + t], s);
    }

    // epilogue: BN + ReLU, store NHWC bf16
    #pragma unroll
    for (int i2 = 0; i2 < 4; ++i2) {
        int co_b = wr * 64 + i2 * 16 + kg * 4;
        float4 g  = *(const float4*)&gamma[co_b];
        float4 vv = *(const float4*)&var[co_b];
        float4 bt = *(const float4*)&beta[co_b];
        float4 mn = *(const float4*)&mean[co_b];
        float inv0 = g.x * rsqrtf(vv.x + 1e-5f), inv1 = g.y * rsqrtf(vv.y + 1e-5f);
        float inv2 = g.z * rsqrtf(vv.z + 1e-5f), inv3 = g.w * rsqrtf(vv.w + 1e-5f);
        float ad0 = bt.x - mn.x * inv0, ad1 = bt.y - mn.y * inv1;
        float ad2 = bt.z - mn.z * inv2, ad3 = bt.w - mn.w * inv3;
        #pragma unroll
        for (int j = 0; j < 4; ++j) {
            int pl = wc * 64 + j * 16 + lr;
            float v0 = fmaxf(acc[i2][j][0] * inv0 + ad0, 0.f);
            float v1 = fmaxf(acc[i2][j][1] * inv1 + ad1, 0.f);
            float v2 = fmaxf(acc[i2][j][2] * inv2 + ad2, 0.f);
            float v3 = fmaxf(acc[i2][j][3] * inv3 + ad3, 0.f);
            uint2 pk;
            pk.x = cvt_pk_bf16(v0, v1);
            pk.y = cvt_pk_bf16(v2, v3);
            *(uint2*)&enh[((size_t)b * HW + p0 + pl) * C_ + co_b] = pk;
        }
    }
}

// ---------------------------------------------------------------------------
// Kernel 2: parallel first-layer MLPs. pooled holds RAW sums (scale by 1/HW).
//   outputs: hk[16][64], hb[16][32]
// ---------------------------------------------------------------------------
__global__ __launch_bounds__(256) void gen_mlp1_kernel(
    const float* __restrict__ pooled,
    const float* __restrict__ kg_w1, const float* __restrict__ kg_b1,
    const float* __restrict__ bg_w1, const float* __restrict__ bg_b1,
    float* __restrict__ hk, float* __restrict__ hb)
{
    const float scale = 1.0f / (float)HW;
    int idx = blockIdx.x * 256 + threadIdx.x;   // 0..1535
    if (idx < B_ * 64) {
        int b = idx >> 6, j = idx & 63;
        const float4* w = (const float4*)(kg_w1 + (size_t)j * TWOC);
        const float4* p = (const float4*)(pooled + b * TWOC);
        float s = 0.f;
        #pragma unroll 8
        for (int q = 0; q < 64; ++q) {
            float4 wv = w[q], pv = p[q];
            s += (wv.x * pv.x + wv.y * pv.y) + (wv.z * pv.z + wv.w * pv.w);
        }
        hk[idx] = fmaxf(kg_b1[j] + s * scale, 0.f);
    } else if (idx < B_ * 64 + B_ * 32) {
        int e = idx - B_ * 64;
        int b = e >> 5, j = e & 31;
        const float4* w = (const float4*)(bg_w1 + (size_t)j * TWOC);
        const float4* p = (const float4*)(pooled + b * TWOC);
        float s = 0.f;
        #pragma unroll 8
        for (int q = 0; q < 64; ++q) {
            float4 wv = w[q], pv = p[q];
            s += (wv.x * pv.x + wv.y * pv.y) + (wv.z * pv.z + wv.w * pv.w);
        }
        hb[e] = fmaxf(bg_b1[j] + s * scale, 0.f);
    }
}

// ---------------------------------------------------------------------------
// Kernel 3: dynamic kernel gen -> dynk[b][kk][o][c] bf16 ; block 0: dyn_b
// ---------------------------------------------------------------------------
__global__ __launch_bounds__(256) void gen_dynk_kernel(
    const float* __restrict__ kg_w2, const float* __restrict__ kg_b2,
    const float* __restrict__ hk, const float* __restrict__ hb,
    const float* __restrict__ bg_w2, const float* __restrict__ bg_b2,
    ushort* __restrict__ dynk, float* __restrict__ dyn_b)
{
    __shared__ float hk_s[B_][64];
    int t = threadIdx.x;
    for (int i = t; i < B_ * 64; i += 256) hk_s[i >> 6][i & 63] = hk[i];
    __syncthreads();

    int i = blockIdx.x * 256 + t;     // dest-linear, 0..147455
    int kk = i >> 14;                 // 9 << 14 == 147456
    int o  = (i >> 7) & 127;
    int c  = i & 127;
    int r  = o * KTOT + c * 9 + kk;   // source row of kg_w2

    float wrow[64];
    const float4* w4 = (const float4*)(kg_w2 + (size_t)r * 64);
    #pragma unroll
    for (int q = 0; q < 16; ++q) {
        float4 v = w4[q];
        wrow[4 * q + 0] = v.x; wrow[4 * q + 1] = v.y;
        wrow[4 * q + 2] = v.z; wrow[4 * q + 3] = v.w;
    }
    float bias = kg_b2[r];
    #pragma unroll
    for (int b = 0; b < B_; ++b) {
        float s = bias;
        #pragma unroll
        for (int k2 = 0; k2 < 64; ++k2) s += hk_s[b][k2] * wrow[k2];
        dynk[((size_t)(b * 9 + kk) * 128 + o) * 128 + c] = f2bf(s);
    }

    if (blockIdx.x == 0) {
        for (int e = t; e < B_ * OUT_; e += 256) {
            int b = e >> 7, o2 = e & 127;
            float s = bg_b2[o2];
            const float* w = bg_w2 + o2 * 32;
            const float* h = hb + b * 32;
            #pragma unroll
            for (int k2 = 0; k2 < 32; ++k2) s += h[k2] * w[k2];
            dyn_b[e] = s;
        }
    }
}

// ---------------------------------------------------------------------------
// Kernel 4: dynamic 3x3 conv, implicit GEMM.
//   v2: block tile = 64 o x (4x32) px, wave tile 64o x 32px -> acc 32 AGPR.
//       Total regs ~115 (unified VGPR+AGPR) -> 4 waves/SIMD, 4 blocks/CU.
//       32-wide px tile => blocks own full 128B output lines (no write split).
//       XCD-chunked block swizzle: each XCD handles exactly 2 images ->
//       dynk + halo stay L2-local; oh-paired blocks share halo via L2.
//   halo: 6x34 px, 64-ch chunks, rows padded to 72 shorts (29.4 KB).
// ---------------------------------------------------------------------------
#define TY_   4
#define TX_   32
#define HX_   34
#define NPX_  204    // 6*34

__global__ __launch_bounds__(256, 4) void dynconv_kernel(
    const ushort* __restrict__ enh, const ushort* __restrict__ dynk,
    const float* __restrict__ dyn_b, float* __restrict__ out)
{
    __shared__ ushort halo[NPX_][72];   // 29376 B
    // chunked XCD swizzle (4096 blocks, 8 XCDs -> 512/XCD = 2 images)
    const int pid = blockIdx.x;
    const int lid = (pid & 7) * 512 + (pid >> 3);
    const int b   = lid >> 8;
    const int rem = lid & 255;           // oh fastest, then tx, then ty
    const int oh  = rem & 1;
    const int tile = rem >> 1;
    const int ty = tile >> 2, tx = tile & 3;
    const int gy0 = ty * TY_, gx0 = tx * TX_;

    const int t = threadIdx.x, lane = t & 63, wc = t >> 6;   // wc = px row 0..3
    const int lr = lane & 15, kg = lane >> 4;
    const ushort* dynk_b = dynk + (size_t)b * 9 * 128 * 128;
    const ushort* enh_b  = enh + (size_t)b * HW * C_;

    floatx4 acc[4][2] = {};
    short8 a_cur[8], a_nxt[8];

    for (int h = 0; h < 2; ++h) {
        // --- load halo regs (204 px x 64 c = 1632 16B segs, 7 passes) ---
        uint4 hreg[7];
        #pragma unroll
        for (int s = 0; s < 7; ++s) {
            int seg = s * 256 + t;
            int hp = seg >> 3, c8 = seg & 7;
            uint4 v = make_uint4(0, 0, 0, 0);
            if (hp < NPX_) {
                int hy = hp / HX_, hx = hp - hy * HX_;
                int gy = gy0 - 1 + hy, gx = gx0 - 1 + hx;
                if ((unsigned)gy < 128u && (unsigned)gx < 128u)
                    v = *(const uint4*)&enh_b[((size_t)(gy * WDIM + gx)) * C_ + h * 64 + c8 * 8];
            }
            hreg[s] = v;
        }
        // --- prefetch A for kk=0 (q = ks*4 + i2) ---
        #pragma unroll
        for (int q = 0; q < 8; ++q) {
            int ks = q >> 2, i2 = q & 3;
            int o = oh * 64 + i2 * 16 + lr;
            a_cur[q] = *(const short8*)&dynk_b[(size_t)(0 * 128 + o) * 128 + h * 64 + ks * 32 + kg * 8];
        }
        __syncthreads();   // previous chunk's halo reads done
        #pragma unroll
        for (int s = 0; s < 7; ++s) {
            int seg = s * 256 + t;
            int hp = seg >> 3, c8 = seg & 7;
            if (hp < NPX_) *(uint4*)&halo[hp][c8 * 8] = hreg[s];
        }
        __syncthreads();   // halo ready; kk loop needs no further barriers

        #pragma unroll
        for (int kk = 0; kk < 9; ++kk) {
            if (kk < 8) {
                #pragma unroll
                for (int q = 0; q < 8; ++q) {
                    int ks = q >> 2, i2 = q & 3;
                    int o = oh * 64 + i2 * 16 + lr;
                    a_nxt[q] = *(const short8*)&dynk_b[(size_t)((kk + 1) * 128 + o) * 128 + h * 64 + ks * 32 + kg * 8];
                }
            }
            const int kh = kk / 3, kw = kk - kh * 3;
            #pragma unroll
            for (int ks = 0; ks < 2; ++ks) {
                short8 bfr[2];
                #pragma unroll
                for (int j = 0; j < 2; ++j)
                    bfr[j] = *(const short8*)&halo[(wc + kh) * HX_ + j * 16 + lr + kw][ks * 32 + kg * 8];
                #pragma unroll
                for (int i2 = 0; i2 < 4; ++i2)
                    #pragma unroll
                    for (int j = 0; j < 2; ++j)
                        acc[i2][j] = __builtin_amdgcn_mfma_f32_16x16x32_bf16(a_cur[ks * 4 + i2], bfr[j], acc[i2][j], 0, 0, 0);
            }
            #pragma unroll
            for (int q = 0; q < 8; ++q) a_cur[q] = a_nxt[q];
        }
    }

    // --- epilogue: + dyn_b, store NCHW fp32 (full 128B lines per block) ---
    const int gy = gy0 + wc;
    #pragma unroll
    for (int i2 = 0; i2 < 4; ++i2) {
        int o_b = oh * 64 + i2 * 16 + kg * 4;
        float4 db = *(const float4*)&dyn_b[b * OUT_ + o_b];
        float dbv[4] = {db.x, db.y, db.z, db.w};
        #pragma unroll
        for (int j = 0; j < 2; ++j) {
            int gx = gx0 + j * 16 + lr;
            #pragma unroll
            for (int r = 0; r < 4; ++r) {
                int o = o_b + r;
                out[((size_t)(b * OUT_ + o)) * HW + gy * WDIM + gx] = acc[i2][j][r] + dbv[r];
            }
        }
    }
}

// ---------------------------------------------------------------------------
extern "C" void kernel_launch(void* const* d_in, const int* in_sizes, int n_in,
                              void* d_out, int out_size, void* d_ws, size_t ws_size,
                              hipStream_t stream)
{
    const float* ir    = (const float*)d_in[0];
    const float* vi    = (const float*)d_in[1];
    const float* kg_w1 = (const float*)d_in[2];
    const float* kg_b1 = (const float*)d_in[3];
    const float* kg_w2 = (const float*)d_in[4];
    const float* kg_b2 = (const float*)d_in[5];
    const float* bg_w1 = (const float*)d_in[6];
    const float* bg_b1 = (const float*)d_in[7];
    const float* bg_w2 = (const float*)d_in[8];
    const float* bg_b2 = (const float*)d_in[9];
    const float* en_w  = (const float*)d_in[10];
    const float* bn_g  = (const float*)d_in[11];
    const float* bn_b  = (const float*)d_in[12];
    const float* bn_m  = (const float*)d_in[13];
    const float* bn_v  = (const float*)d_in[14];
    float* out = (float*)d_out;

    char* ws = (char*)d_ws;
    float*  pooled = (float*)(ws + 0);                    // 16 KB
    float*  dyn_b  = (float*)(ws + 16384);                // 8 KB
    float*  hk     = (float*)(ws + 24576);                // 4 KB
    float*  hb     = (float*)(ws + 28672);                // 2 KB
    ushort* dynk   = (ushort*)(ws + 32768);               // 4.72 MB [b][kk][o][c]
    ushort* enh    = (ushort*)(ws + 32768 + 4718592);     // 64 MB NHWC bf16

    // bf16 copy of en_w (64 KB): use ws tail if it fits, else stash in out's
    // tail (out is only written by the final dynconv kernel -> stream-safe).
    size_t en_off = 32768 + 4718592 + 67108864;
    ushort* en_w_bf = (ws_size >= en_off + 65536)
                    ? (ushort*)(ws + en_off)
                    : (ushort*)((char*)d_out + (size_t)out_size - 65536);

    prep_kernel<<<128, 256, 0, stream>>>(en_w, en_w_bf, pooled);
    enhance_kernel<<<dim3(HDIM, B_), 256, 0, stream>>>(ir, vi, en_w_bf, bn_g, bn_b,
                                                       bn_m, bn_v, enh, pooled);
    gen_mlp1_kernel<<<6, 256, 0, stream>>>(pooled, kg_w1, kg_b1, bg_w1, bg_b1, hk, hb);
    gen_dynk_kernel<<<576, 256, 0, stream>>>(kg_w2, kg_b2, hk, hb, bg_w2, bg_b2, dynk, dyn_b);
    dynconv_kernel<<<4096, 256, 0, stream>>>(enh, dynk, dyn_b, out);
}

// Round 5
// 591.451 us; speedup vs baseline: 1.1241x; 1.1241x over previous
//
#include <hip/hip_runtime.h>
#include <hip/hip_bf16.h>

#define B_    16
#define C_    128
#define TWOC  256
#define OUT_  128
#define HW    16384
#define WDIM  128
#define HDIM  128
#define KTOT  1152

typedef __attribute__((ext_vector_type(8))) short short8;
typedef __attribute__((ext_vector_type(4))) float floatx4;

__device__ __forceinline__ ushort f2bf(float f) {
    union { float f; uint u; } x; x.f = f;
    uint r = (x.u + 0x7FFFu + ((x.u >> 16) & 1u)) >> 16;   // RNE
    return (ushort)r;
}
__device__ __forceinline__ float bf2f(ushort u) {
    union { float f; uint u; } x; x.u = ((uint)u) << 16;
    return x.f;
}
// HW packed f32->bf16 (RNE, identical to f2bf on finite values), 1 instr per pair
__device__ __forceinline__ uint cvt_pk_bf16(float lo, float hi) {
    uint r;
    asm("v_cvt_pk_bf16_f32 %0, %1, %2" : "=v"(r) : "v"(lo), "v"(hi));
    return r;
}

// ---------------------------------------------------------------------------
// prep: en_w fp32 -> bf16 (once) + zero pooled accumulator
// ---------------------------------------------------------------------------
__global__ __launch_bounds__(256) void prep_kernel(
    const float* __restrict__ en_w, ushort* __restrict__ en_w_bf,
    float* __restrict__ pooled)
{
    int i = blockIdx.x * 256 + threadIdx.x;    // 0..32767
    en_w_bf[i] = f2bf(en_w[i]);
    if (i < B_ * TWOC) pooled[i] = 0.f;
}

// ---------------------------------------------------------------------------
// Kernel 1 (fused): enhance = relu(BN(concat @ en_w^T)) -> enh bf16 NHWC
//                   + global-average-pool partial sums -> atomicAdd(pooled)
//   Per block: one image row (128 px) of one b. K=256 in 8 chunks of 32.
//   chunk-ahead software pipeline; pre-converted bf16 weights; HW packed
//   converts; pool reduce folded into the main-loop barriers.
// ---------------------------------------------------------------------------
__global__ __launch_bounds__(256) void enhance_kernel(
    const float* __restrict__ ir, const float* __restrict__ vi,
    const ushort* __restrict__ en_w_bf,
    const float* __restrict__ gamma, const float* __restrict__ beta,
    const float* __restrict__ mean, const float* __restrict__ var,
    ushort* __restrict__ enh, float* __restrict__ pooled)
{
    __shared__ ushort Xs[128][40];   // pad 32->40 shorts
    __shared__ float red[256];
    const int b = blockIdx.y;
    const int p0 = blockIdx.x * 128;
    const int t = threadIdx.x;
    const int lane = t & 63, wave = t >> 6;
    const int wr = wave >> 1, wc = wave & 1;
    const int lr = lane & 15, kg = lane >> 4;
    const int px = t & 127, half = t >> 7;
    const int pc = t & 31, grp = t >> 5;

    floatx4 acc[4][4] = {};
    float fcur[16], fnxt[16];
    short8 a_cur[4], a_nxt[4];

    // prologue: input chunk 0 + weight chunk 0 (only exposed latency)
    {
        const float* src = ir + ((size_t)b * C_ + half * 16) * HW + p0 + px;
        #pragma unroll
        for (int jj = 0; jj < 16; ++jj) fcur[jj] = src[(size_t)jj * HW];
        #pragma unroll
        for (int i2 = 0; i2 < 4; ++i2) {
            int co = wr * 64 + i2 * 16 + lr;
            a_cur[i2] = *(const short8*)&en_w_bf[(size_t)co * TWOC + kg * 8];
        }
    }

    #pragma unroll
    for (int kc = 0; kc < 8; ++kc) {
        __syncthreads();     // (a) Xs reads of kc-1 done  (b) red[] of kc-1 complete
        {   // pack + stage chunk kc
            uint u[8];
            #pragma unroll
            for (int jj = 0; jj < 8; ++jj)
                u[jj] = cvt_pk_bf16(fcur[2 * jj], fcur[2 * jj + 1]);
            uint4* dst = (uint4*)&Xs[px][half * 16];
            dst[0] = make_uint4(u[0], u[1], u[2], u[3]);
            dst[1] = make_uint4(u[4], u[5], u[6], u[7]);
        }
        if (kc > 0 && t < 32) {   // pool finalize for chunk kc-1 (reads red)
            float s = red[t] + red[32 + t] + red[64 + t] + red[96 + t]
                    + red[128 + t] + red[160 + t] + red[192 + t] + red[224 + t];
            atomicAdd(&pooled[b * TWOC + (kc - 1) * 32 + t], s);
        }
        __syncthreads();     // Xs visible

        // prefetch chunk kc+1 (input + weights) — hidden under MFMA phase below
        if (kc < 7) {
            int c2b = (kc + 1) * 32 + half * 16;
            const float* src = (c2b < C_)
                ? ir + ((size_t)b * C_ + c2b) * HW + p0 + px
                : vi + ((size_t)b * C_ + (c2b - C_)) * HW + p0 + px;
            #pragma unroll
            for (int jj = 0; jj < 16; ++jj) fnxt[jj] = src[(size_t)jj * HW];
            #pragma unroll
            for (int i2 = 0; i2 < 4; ++i2) {
                int co = wr * 64 + i2 * 16 + lr;
                a_nxt[i2] = *(const short8*)&en_w_bf[(size_t)co * TWOC + (kc + 1) * 32 + kg * 8];
            }
        }

        // MFMA phase
        short8 bfr[4];
        #pragma unroll
        for (int j = 0; j < 4; ++j) {
            int pl = wc * 64 + j * 16 + lr;
            bfr[j] = *(const short8*)&Xs[pl][kg * 8];
        }
        #pragma unroll
        for (int i2 = 0; i2 < 4; ++i2)
            #pragma unroll
            for (int j = 0; j < 4; ++j)
                acc[i2][j] = __builtin_amdgcn_mfma_f32_16x16x32_bf16(a_cur[i2], bfr[j], acc[i2][j], 0, 0, 0);

        // pool partial: thread t sums channel (kc*32 + pc) over 16 pixels
        {
            float s = 0.f;
            #pragma unroll
            for (int q = 0; q < 16; ++q) s += bf2f(Xs[grp * 16 + q][pc]);
            red[t] = s;
        }

        if (kc < 7) {
            #pragma unroll
            for (int jj = 0; jj < 16; ++jj) fcur[jj] = fnxt[jj];
            #pragma unroll
            for (int i2 = 0; i2 < 4; ++i2) a_cur[i2] = a_nxt[i2];
        }
    }

    __syncthreads();
    if (t < 32) {   // pool finalize for chunk 7
        float s = red[t] + red[32 + t] + red[64 + t] + red[96 + t]
                + red[128 + t] + red[160 + t] + red[192 + t] + red[224 + t];
        atomicAdd(&pooled[b * TWOC + 7 * 32 + t], s);
    }

    // epilogue: BN + ReLU, store NHWC bf16
    #pragma unroll
    for (int i2 = 0; i2 < 4; ++i2) {
        int co_b = wr * 64 + i2 * 16 + kg * 4;
        float4 g  = *(const float4*)&gamma[co_b];
        float4 vv = *(const float4*)&var[co_b];
        float4 bt = *(const float4*)&beta[co_b];
        float4 mn = *(const float4*)&mean[co_b];
        float inv0 = g.x * rsqrtf(vv.x + 1e-5f), inv1 = g.y * rsqrtf(vv.y + 1e-5f);
        float inv2 = g.z * rsqrtf(vv.z + 1e-5f), inv3 = g.w * rsqrtf(vv.w + 1e-5f);
        float ad0 = bt.x - mn.x * inv0, ad1 = bt.y - mn.y * inv1;
        float ad2 = bt.z - mn.z * inv2, ad3 = bt.w - mn.w * inv3;
        #pragma unroll
        for (int j = 0; j < 4; ++j) {
            int pl = wc * 64 + j * 16 + lr;
            float v0 = fmaxf(acc[i2][j][0] * inv0 + ad0, 0.f);
            float v1 = fmaxf(acc[i2][j][1] * inv1 + ad1, 0.f);
            float v2 = fmaxf(acc[i2][j][2] * inv2 + ad2, 0.f);
            float v3 = fmaxf(acc[i2][j][3] * inv3 + ad3, 0.f);
            uint2 pk;
            pk.x = cvt_pk_bf16(v0, v1);
            pk.y = cvt_pk_bf16(v2, v3);
            *(uint2*)&enh[((size_t)b * HW + p0 + pl) * C_ + co_b] = pk;
        }
    }
}

// ---------------------------------------------------------------------------
// Kernel 2: parallel first-layer MLPs. pooled holds RAW sums (scale by 1/HW).
//   outputs: hk[16][64], hb[16][32]
// ---------------------------------------------------------------------------
__global__ __launch_bounds__(256) void gen_mlp1_kernel(
    const float* __restrict__ pooled,
    const float* __restrict__ kg_w1, const float* __restrict__ kg_b1,
    const float* __restrict__ bg_w1, const float* __restrict__ bg_b1,
    float* __restrict__ hk, float* __restrict__ hb)
{
    const float scale = 1.0f / (float)HW;
    int idx = blockIdx.x * 256 + threadIdx.x;   // 0..1535
    if (idx < B_ * 64) {
        int b = idx >> 6, j = idx & 63;
        const float4* w = (const float4*)(kg_w1 + (size_t)j * TWOC);
        const float4* p = (const float4*)(pooled + b * TWOC);
        float s = 0.f;
        #pragma unroll 8
        for (int q = 0; q < 64; ++q) {
            float4 wv = w[q], pv = p[q];
            s += (wv.x * pv.x + wv.y * pv.y) + (wv.z * pv.z + wv.w * pv.w);
        }
        hk[idx] = fmaxf(kg_b1[j] + s * scale, 0.f);
    } else if (idx < B_ * 64 + B_ * 32) {
        int e = idx - B_ * 64;
        int b = e >> 5, j = e & 31;
        const float4* w = (const float4*)(bg_w1 + (size_t)j * TWOC);
        const float4* p = (const float4*)(pooled + b * TWOC);
        float s = 0.f;
        #pragma unroll 8
        for (int q = 0; q < 64; ++q) {
            float4 wv = w[q], pv = p[q];
            s += (wv.x * pv.x + wv.y * pv.y) + (wv.z * pv.z + wv.w * pv.w);
        }
        hb[e] = fmaxf(bg_b1[j] + s * scale, 0.f);
    }
}

// ---------------------------------------------------------------------------
// Kernel 3: dynamic kernel gen -> dynk[b][kk][o][c] bf16 ; block 0: dyn_b
// ---------------------------------------------------------------------------
__global__ __launch_bounds__(256) void gen_dynk_kernel(
    const float* __restrict__ kg_w2, const float* __restrict__ kg_b2,
    const float* __restrict__ hk, const float* __restrict__ hb,
    const float* __restrict__ bg_w2, const float* __restrict__ bg_b2,
    ushort* __restrict__ dynk, float* __restrict__ dyn_b)
{
    __shared__ float hk_s[B_][64];
    int t = threadIdx.x;
    for (int i = t; i < B_ * 64; i += 256) hk_s[i >> 6][i & 63] = hk[i];
    __syncthreads();

    int i = blockIdx.x * 256 + t;     // dest-linear, 0..147455
    int kk = i >> 14;                 // 9 << 14 == 147456
    int o  = (i >> 7) & 127;
    int c  = i & 127;
    int r  = o * KTOT + c * 9 + kk;   // source row of kg_w2

    float wrow[64];
    const float4* w4 = (const float4*)(kg_w2 + (size_t)r * 64);
    #pragma unroll
    for (int q = 0; q < 16; ++q) {
        float4 v = w4[q];
        wrow[4 * q + 0] = v.x; wrow[4 * q + 1] = v.y;
        wrow[4 * q + 2] = v.z; wrow[4 * q + 3] = v.w;
    }
    float bias = kg_b2[r];
    #pragma unroll
    for (int b = 0; b < B_; ++b) {
        float s = bias;
        #pragma unroll
        for (int k2 = 0; k2 < 64; ++k2) s += hk_s[b][k2] * wrow[k2];
        dynk[((size_t)(b * 9 + kk) * 128 + o) * 128 + c] = f2bf(s);
    }

    if (blockIdx.x == 0) {
        for (int e = t; e < B_ * OUT_; e += 256) {
            int b = e >> 7, o2 = e & 127;
            float s = bg_b2[o2];
            const float* w = bg_w2 + o2 * 32;
            const float* h = hb + b * 32;
            #pragma unroll
            for (int k2 = 0; k2 < 32; ++k2) s += h[k2] * w[k2];
            dyn_b[e] = s;
        }
    }
}

// ---------------------------------------------------------------------------
// Kernel 4: dynamic 3x3 conv, implicit GEMM.
//   v3: block tile = 128 o x (4x32) px (2048 blocks), wave tile 64o x 64px
//       (v1's 2:1 MFMA:ds_read economics, 2x A-redundancy). A-frags loaded
//       per-ks DIRECTLY from global (no cross-kk prefetch) -> ~112 live regs
//       -> __launch_bounds__(256,4) without squeeze; latency hidden by TLP.
//       32-wide px tile => full 128B output lines. Image-chunked XCD swizzle.
//   halo: 6x34 px, 64-ch chunks, rows padded to 72 shorts (29.4 KB).
// ---------------------------------------------------------------------------
#define TY_   4
#define TX_   32
#define HX_   34
#define NPX_  204    // 6*34

__global__ __launch_bounds__(256, 4) void dynconv_kernel(
    const ushort* __restrict__ enh, const ushort* __restrict__ dynk,
    const float* __restrict__ dyn_b, float* __restrict__ out)
{
    __shared__ ushort halo[NPX_][72];   // 29376 B
    // chunked XCD swizzle (2048 blocks, 8 XCDs -> 256/XCD = 2 images)
    const int pid = blockIdx.x;
    const int lid = (pid & 7) * 256 + (pid >> 3);
    const int b   = lid >> 7;
    const int rem = lid & 127;          // tx fastest, then ty
    const int ty = rem >> 2, tx = rem & 3;
    const int gy0 = ty * TY_, gx0 = tx * TX_;

    const int t = threadIdx.x, lane = t & 63, wave = t >> 6;
    const int wr = wave >> 1, wc = wave & 1;
    const int lr = lane & 15, kg = lane >> 4;
    const ushort* dynk_b = dynk + (size_t)b * 9 * 128 * 128;
    const ushort* enh_b  = enh + (size_t)b * HW * C_;

    floatx4 acc[4][4] = {};

    for (int h = 0; h < 2; ++h) {
        // --- load halo regs (204 px x 64 c = 1632 16B segs, 7 passes) ---
        uint4 hreg[7];
        #pragma unroll
        for (int s = 0; s < 7; ++s) {
            int seg = s * 256 + t;
            int hp = seg >> 3, c8 = seg & 7;
            uint4 v = make_uint4(0, 0, 0, 0);
            if (hp < NPX_) {
                int hy = hp / HX_, hx = hp - hy * HX_;
                int gy = gy0 - 1 + hy, gx = gx0 - 1 + hx;
                if ((unsigned)gy < 128u && (unsigned)gx < 128u)
                    v = *(const uint4*)&enh_b[((size_t)(gy * WDIM + gx)) * C_ + h * 64 + c8 * 8];
            }
            hreg[s] = v;
        }
        __syncthreads();   // previous chunk's halo reads done
        #pragma unroll
        for (int s = 0; s < 7; ++s) {
            int seg = s * 256 + t;
            int hp = seg >> 3, c8 = seg & 7;
            if (hp < NPX_) *(uint4*)&halo[hp][c8 * 8] = hreg[s];
        }
        __syncthreads();   // halo ready; kk loop needs no further barriers

        #pragma unroll
        for (int kk = 0; kk < 9; ++kk) {
            const int kh = kk / 3, kw = kk - kh * 3;
            #pragma unroll
            for (int ks = 0; ks < 2; ++ks) {
                short8 a[4], bfr[4];
                #pragma unroll
                for (int i2 = 0; i2 < 4; ++i2) {
                    int o = wr * 64 + i2 * 16 + lr;
                    a[i2] = *(const short8*)&dynk_b[(size_t)(kk * 128 + o) * 128 + h * 64 + ks * 32 + kg * 8];
                }
                #pragma unroll
                for (int j = 0; j < 4; ++j) {
                    int p = wc * 64 + j * 16 + lr;
                    int py = p >> 5, pxc = p & 31;
                    bfr[j] = *(const short8*)&halo[(py + kh) * HX_ + pxc + kw][ks * 32 + kg * 8];
                }
                #pragma unroll
                for (int i2 = 0; i2 < 4; ++i2)
                    #pragma unroll
                    for (int j = 0; j < 4; ++j)
                        acc[i2][j] = __builtin_amdgcn_mfma_f32_16x16x32_bf16(a[i2], bfr[j], acc[i2][j], 0, 0, 0);
            }
        }
    }

    // --- epilogue: + dyn_b, store NCHW fp32 (full 128B lines per block) ---
    #pragma unroll
    for (int i2 = 0; i2 < 4; ++i2) {
        int o_b = wr * 64 + i2 * 16 + kg * 4;
        float4 db = *(const float4*)&dyn_b[b * OUT_ + o_b];
        float dbv[4] = {db.x, db.y, db.z, db.w};
        #pragma unroll
        for (int j = 0; j < 4; ++j) {
            int p = wc * 64 + j * 16 + lr;
            int py = p >> 5, pxc = p & 31;
            int gy = gy0 + py, gx = gx0 + pxc;
            #pragma unroll
            for (int r = 0; r < 4; ++r) {
                int o = o_b + r;
                out[((size_t)(b * OUT_ + o)) * HW + gy * WDIM + gx] = acc[i2][j][r] + dbv[r];
            }
        }
    }
}

// ---------------------------------------------------------------------------
extern "C" void kernel_launch(void* const* d_in, const int* in_sizes, int n_in,
                              void* d_out, int out_size, void* d_ws, size_t ws_size,
                              hipStream_t stream)
{
    const float* ir    = (const float*)d_in[0];
    const float* vi    = (const float*)d_in[1];
    const float* kg_w1 = (const float*)d_in[2];
    const float* kg_b1 = (const float*)d_in[3];
    const float* kg_w2 = (const float*)d_in[4];
    const float* kg_b2 = (const float*)d_in[5];
    const float* bg_w1 = (const float*)d_in[6];
    const float* bg_b1 = (const float*)d_in[7];
    const float* bg_w2 = (const float*)d_in[8];
    const float* bg_b2 = (const float*)d_in[9];
    const float* en_w  = (const float*)d_in[10];
    const float* bn_g  = (const float*)d_in[11];
    const float* bn_b  = (const float*)d_in[12];
    const float* bn_m  = (const float*)d_in[13];
    const float* bn_v  = (const float*)d_in[14];
    float* out = (float*)d_out;

    char* ws = (char*)d_ws;
    float*  pooled = (float*)(ws + 0);                    // 16 KB
    float*  dyn_b  = (float*)(ws + 16384);                // 8 KB
    float*  hk     = (float*)(ws + 24576);                // 4 KB
    float*  hb     = (float*)(ws + 28672);                // 2 KB
    ushort* dynk   = (ushort*)(ws + 32768);               // 4.72 MB [b][kk][o][c]
    ushort* enh    = (ushort*)(ws + 32768 + 4718592);     // 64 MB NHWC bf16

    // bf16 copy of en_w (64 KB): use ws tail if it fits, else stash in out's
    // tail (out is only written by the final dynconv kernel -> stream-safe).
    size_t en_off = 32768 + 4718592 + 67108864;
    ushort* en_w_bf = (ws_size >= en_off + 65536)
                    ? (ushort*)(ws + en_off)
                    : (ushort*)((char*)d_out + (size_t)out_size - 65536);

    prep_kernel<<<128, 256, 0, stream>>>(en_w, en_w_bf, pooled);
    enhance_kernel<<<dim3(HDIM, B_), 256, 0, stream>>>(ir, vi, en_w_bf, bn_g, bn_b,
                                                       bn_m, bn_v, enh, pooled);
    gen_mlp1_kernel<<<6, 256, 0, stream>>>(pooled, kg_w1, kg_b1, bg_w1, bg_b1, hk, hb);
    gen_dynk_kernel<<<576, 256, 0, stream>>>(kg_w2, kg_b2, hk, hb, bg_w2, bg_b2, dynk, dyn_b);
    dynconv_kernel<<<2048, 256, 0, stream>>>(enh, dynk, dyn_b, out);
}

// Round 6
// 562.554 us; speedup vs baseline: 1.1818x; 1.0514x over previous
//
#include <hip/hip_runtime.h>
#include <hip/hip_bf16.h>

#define B_    16
#define C_    128
#define TWOC  256
#define OUT_  128
#define HW    16384
#define WDIM  128
#define HDIM  128
#define KTOT  1152

typedef __attribute__((ext_vector_type(8))) short short8;
typedef __attribute__((ext_vector_type(4))) float floatx4;

__device__ __forceinline__ ushort f2bf(float f) {
    union { float f; uint u; } x; x.f = f;
    uint r = (x.u + 0x7FFFu + ((x.u >> 16) & 1u)) >> 16;   // RNE
    return (ushort)r;
}
__device__ __forceinline__ float bf2f(ushort u) {
    union { float f; uint u; } x; x.u = ((uint)u) << 16;
    return x.f;
}
// HW packed f32->bf16 (RNE, identical to f2bf on finite values), 1 instr per pair
__device__ __forceinline__ uint cvt_pk_bf16(float lo, float hi) {
    uint r;
    asm("v_cvt_pk_bf16_f32 %0, %1, %2" : "=v"(r) : "v"(lo), "v"(hi));
    return r;
}

// ---------------------------------------------------------------------------
// prep: en_w fp32 -> bf16 (once) + zero pooled accumulator
// ---------------------------------------------------------------------------
__global__ __launch_bounds__(256) void prep_kernel(
    const float* __restrict__ en_w, ushort* __restrict__ en_w_bf,
    float* __restrict__ pooled)
{
    int i = blockIdx.x * 256 + threadIdx.x;    // 0..32767
    en_w_bf[i] = f2bf(en_w[i]);
    if (i < B_ * TWOC) pooled[i] = 0.f;
}

// ---------------------------------------------------------------------------
// Kernel 1 (fused): enhance = relu(BN(concat @ en_w^T)) -> enh bf16 NHWC
//                   + global-average-pool partial sums -> atomicAdd(pooled)
//   Per block: one image row (128 px) of one b. K=256 in 8 chunks of 32.
//   chunk-ahead software pipeline; pre-converted bf16 weights; HW packed
//   converts; pool reduce folded into the main-loop barriers.
// ---------------------------------------------------------------------------
__global__ __launch_bounds__(256) void enhance_kernel(
    const float* __restrict__ ir, const float* __restrict__ vi,
    const ushort* __restrict__ en_w_bf,
    const float* __restrict__ gamma, const float* __restrict__ beta,
    const float* __restrict__ mean, const float* __restrict__ var,
    ushort* __restrict__ enh, float* __restrict__ pooled)
{
    __shared__ ushort Xs[128][40];   // pad 32->40 shorts
    __shared__ float red[256];
    const int b = blockIdx.y;
    const int p0 = blockIdx.x * 128;
    const int t = threadIdx.x;
    const int lane = t & 63, wave = t >> 6;
    const int wr = wave >> 1, wc = wave & 1;
    const int lr = lane & 15, kg = lane >> 4;
    const int px = t & 127, half = t >> 7;
    const int pc = t & 31, grp = t >> 5;

    floatx4 acc[4][4] = {};
    float fcur[16], fnxt[16];
    short8 a_cur[4], a_nxt[4];

    // prologue: input chunk 0 + weight chunk 0 (only exposed latency)
    {
        const float* src = ir + ((size_t)b * C_ + half * 16) * HW + p0 + px;
        #pragma unroll
        for (int jj = 0; jj < 16; ++jj) fcur[jj] = src[(size_t)jj * HW];
        #pragma unroll
        for (int i2 = 0; i2 < 4; ++i2) {
            int co = wr * 64 + i2 * 16 + lr;
            a_cur[i2] = *(const short8*)&en_w_bf[(size_t)co * TWOC + kg * 8];
        }
    }

    #pragma unroll
    for (int kc = 0; kc < 8; ++kc) {
        __syncthreads();     // (a) Xs reads of kc-1 done  (b) red[] of kc-1 complete
        {   // pack + stage chunk kc
            uint u[8];
            #pragma unroll
            for (int jj = 0; jj < 8; ++jj)
                u[jj] = cvt_pk_bf16(fcur[2 * jj], fcur[2 * jj + 1]);
            uint4* dst = (uint4*)&Xs[px][half * 16];
            dst[0] = make_uint4(u[0], u[1], u[2], u[3]);
            dst[1] = make_uint4(u[4], u[5], u[6], u[7]);
        }
        if (kc > 0 && t < 32) {   // pool finalize for chunk kc-1 (reads red)
            float s = red[t] + red[32 + t] + red[64 + t] + red[96 + t]
                    + red[128 + t] + red[160 + t] + red[192 + t] + red[224 + t];
            atomicAdd(&pooled[b * TWOC + (kc - 1) * 32 + t], s);
        }
        __syncthreads();     // Xs visible

        // prefetch chunk kc+1 (input + weights) — hidden under MFMA phase below
        if (kc < 7) {
            int c2b = (kc + 1) * 32 + half * 16;
            const float* src = (c2b < C_)
                ? ir + ((size_t)b * C_ + c2b) * HW + p0 + px
                : vi + ((size_t)b * C_ + (c2b - C_)) * HW + p0 + px;
            #pragma unroll
            for (int jj = 0; jj < 16; ++jj) fnxt[jj] = src[(size_t)jj * HW];
            #pragma unroll
            for (int i2 = 0; i2 < 4; ++i2) {
                int co = wr * 64 + i2 * 16 + lr;
                a_nxt[i2] = *(const short8*)&en_w_bf[(size_t)co * TWOC + (kc + 1) * 32 + kg * 8];
            }
        }

        // MFMA phase
        short8 bfr[4];
        #pragma unroll
        for (int j = 0; j < 4; ++j) {
            int pl = wc * 64 + j * 16 + lr;
            bfr[j] = *(const short8*)&Xs[pl][kg * 8];
        }
        #pragma unroll
        for (int i2 = 0; i2 < 4; ++i2)
            #pragma unroll
            for (int j = 0; j < 4; ++j)
                acc[i2][j] = __builtin_amdgcn_mfma_f32_16x16x32_bf16(a_cur[i2], bfr[j], acc[i2][j], 0, 0, 0);

        // pool partial: thread t sums channel (kc*32 + pc) over 16 pixels
        {
            float s = 0.f;
            #pragma unroll
            for (int q = 0; q < 16; ++q) s += bf2f(Xs[grp * 16 + q][pc]);
            red[t] = s;
        }

        if (kc < 7) {
            #pragma unroll
            for (int jj = 0; jj < 16; ++jj) fcur[jj] = fnxt[jj];
            #pragma unroll
            for (int i2 = 0; i2 < 4; ++i2) a_cur[i2] = a_nxt[i2];
        }
    }

    __syncthreads();
    if (t < 32) {   // pool finalize for chunk 7
        float s = red[t] + red[32 + t] + red[64 + t] + red[96 + t]
                + red[128 + t] + red[160 + t] + red[192 + t] + red[224 + t];
        atomicAdd(&pooled[b * TWOC + 7 * 32 + t], s);
    }

    // epilogue: BN + ReLU, store NHWC bf16
    #pragma unroll
    for (int i2 = 0; i2 < 4; ++i2) {
        int co_b = wr * 64 + i2 * 16 + kg * 4;
        float4 g  = *(const float4*)&gamma[co_b];
        float4 vv = *(const float4*)&var[co_b];
        float4 bt = *(const float4*)&beta[co_b];
        float4 mn = *(const float4*)&mean[co_b];
        float inv0 = g.x * rsqrtf(vv.x + 1e-5f), inv1 = g.y * rsqrtf(vv.y + 1e-5f);
        float inv2 = g.z * rsqrtf(vv.z + 1e-5f), inv3 = g.w * rsqrtf(vv.w + 1e-5f);
        float ad0 = bt.x - mn.x * inv0, ad1 = bt.y - mn.y * inv1;
        float ad2 = bt.z - mn.z * inv2, ad3 = bt.w - mn.w * inv3;
        #pragma unroll
        for (int j = 0; j < 4; ++j) {
            int pl = wc * 64 + j * 16 + lr;
            float v0 = fmaxf(acc[i2][j][0] * inv0 + ad0, 0.f);
            float v1 = fmaxf(acc[i2][j][1] * inv1 + ad1, 0.f);
            float v2 = fmaxf(acc[i2][j][2] * inv2 + ad2, 0.f);
            float v3 = fmaxf(acc[i2][j][3] * inv3 + ad3, 0.f);
            uint2 pk;
            pk.x = cvt_pk_bf16(v0, v1);
            pk.y = cvt_pk_bf16(v2, v3);
            *(uint2*)&enh[((size_t)b * HW + p0 + pl) * C_ + co_b] = pk;
        }
    }
}

// ---------------------------------------------------------------------------
// Kernel 2: parallel first-layer MLPs. pooled holds RAW sums (scale by 1/HW).
//   outputs: hk[16][64], hb[16][32]
// ---------------------------------------------------------------------------
__global__ __launch_bounds__(256) void gen_mlp1_kernel(
    const float* __restrict__ pooled,
    const float* __restrict__ kg_w1, const float* __restrict__ kg_b1,
    const float* __restrict__ bg_w1, const float* __restrict__ bg_b1,
    float* __restrict__ hk, float* __restrict__ hb)
{
    const float scale = 1.0f / (float)HW;
    int idx = blockIdx.x * 256 + threadIdx.x;   // 0..1535
    if (idx < B_ * 64) {
        int b = idx >> 6, j = idx & 63;
        const float4* w = (const float4*)(kg_w1 + (size_t)j * TWOC);
        const float4* p = (const float4*)(pooled + b * TWOC);
        float s = 0.f;
        #pragma unroll 8
        for (int q = 0; q < 64; ++q) {
            float4 wv = w[q], pv = p[q];
            s += (wv.x * pv.x + wv.y * pv.y) + (wv.z * pv.z + wv.w * pv.w);
        }
        hk[idx] = fmaxf(kg_b1[j] + s * scale, 0.f);
    } else if (idx < B_ * 64 + B_ * 32) {
        int e = idx - B_ * 64;
        int b = e >> 5, j = e & 31;
        const float4* w = (const float4*)(bg_w1 + (size_t)j * TWOC);
        const float4* p = (const float4*)(pooled + b * TWOC);
        float s = 0.f;
        #pragma unroll 8
        for (int q = 0; q < 64; ++q) {
            float4 wv = w[q], pv = p[q];
            s += (wv.x * pv.x + wv.y * pv.y) + (wv.z * pv.z + wv.w * pv.w);
        }
        hb[e] = fmaxf(bg_b1[j] + s * scale, 0.f);
    }
}

// ---------------------------------------------------------------------------
// Kernel 3: dynamic kernel gen -> dynk[b][kk][o][c] bf16 ; block 0: dyn_b
// ---------------------------------------------------------------------------
__global__ __launch_bounds__(256) void gen_dynk_kernel(
    const float* __restrict__ kg_w2, const float* __restrict__ kg_b2,
    const float* __restrict__ hk, const float* __restrict__ hb,
    const float* __restrict__ bg_w2, const float* __restrict__ bg_b2,
    ushort* __restrict__ dynk, float* __restrict__ dyn_b)
{
    __shared__ float hk_s[B_][64];
    int t = threadIdx.x;
    for (int i = t; i < B_ * 64; i += 256) hk_s[i >> 6][i & 63] = hk[i];
    __syncthreads();

    int i = blockIdx.x * 256 + t;     // dest-linear, 0..147455
    int kk = i >> 14;                 // 9 << 14 == 147456
    int o  = (i >> 7) & 127;
    int c  = i & 127;
    int r  = o * KTOT + c * 9 + kk;   // source row of kg_w2

    float wrow[64];
    const float4* w4 = (const float4*)(kg_w2 + (size_t)r * 64);
    #pragma unroll
    for (int q = 0; q < 16; ++q) {
        float4 v = w4[q];
        wrow[4 * q + 0] = v.x; wrow[4 * q + 1] = v.y;
        wrow[4 * q + 2] = v.z; wrow[4 * q + 3] = v.w;
    }
    float bias = kg_b2[r];
    #pragma unroll
    for (int b = 0; b < B_; ++b) {
        float s = bias;
        #pragma unroll
        for (int k2 = 0; k2 < 64; ++k2) s += hk_s[b][k2] * wrow[k2];
        dynk[((size_t)(b * 9 + kk) * 128 + o) * 128 + c] = f2bf(s);
    }

    if (blockIdx.x == 0) {
        for (int e = t; e < B_ * OUT_; e += 256) {
            int b = e >> 7, o2 = e & 127;
            float s = bg_b2[o2];
            const float* w = bg_w2 + o2 * 32;
            const float* h = hb + b * 32;
            #pragma unroll
            for (int k2 = 0; k2 < 32; ++k2) s += h[k2] * w[k2];
            dyn_b[e] = s;
        }
    }
}

// ---------------------------------------------------------------------------
// Kernel 4: dynamic 3x3 conv, implicit GEMM.
//   v4: v3 tile (128o x 4x32 px, 2048 blocks, full-128B-line writes,
//       image-chunked XCD swizzle) but __launch_bounds__(256,3): cap ~170
//       regs -> NO scratch spill (v3's (256,4)=128-reg cap spilled ~138 MB).
//       A-frags for both ks batched at top of each kk (8 global loads) for
//       deeper VMEM overlap; kk loop barrier-free.
//   halo: 6x34 px, 64-ch chunks, rows padded to 72 shorts (29.4 KB).
// ---------------------------------------------------------------------------
#define TY_   4
#define TX_   32
#define HX_   34
#define NPX_  204    // 6*34

__global__ __launch_bounds__(256, 3) void dynconv_kernel(
    const ushort* __restrict__ enh, const ushort* __restrict__ dynk,
    const float* __restrict__ dyn_b, float* __restrict__ out)
{
    __shared__ ushort halo[NPX_][72];   // 29376 B
    // chunked XCD swizzle (2048 blocks, 8 XCDs -> 256/XCD = 2 images)
    const int pid = blockIdx.x;
    const int lid = (pid & 7) * 256 + (pid >> 3);
    const int b   = lid >> 7;
    const int rem = lid & 127;          // tx fastest, then ty
    const int ty = rem >> 2, tx = rem & 3;
    const int gy0 = ty * TY_, gx0 = tx * TX_;

    const int t = threadIdx.x, lane = t & 63, wave = t >> 6;
    const int wr = wave >> 1, wc = wave & 1;
    const int lr = lane & 15, kg = lane >> 4;
    const ushort* dynk_b = dynk + (size_t)b * 9 * 128 * 128;
    const ushort* enh_b  = enh + (size_t)b * HW * C_;

    floatx4 acc[4][4] = {};

    for (int h = 0; h < 2; ++h) {
        // --- load halo regs (204 px x 64 c = 1632 16B segs, 7 passes) ---
        uint4 hreg[7];
        #pragma unroll
        for (int s = 0; s < 7; ++s) {
            int seg = s * 256 + t;
            int hp = seg >> 3, c8 = seg & 7;
            uint4 v = make_uint4(0, 0, 0, 0);
            if (hp < NPX_) {
                int hy = hp / HX_, hx = hp - hy * HX_;
                int gy = gy0 - 1 + hy, gx = gx0 - 1 + hx;
                if ((unsigned)gy < 128u && (unsigned)gx < 128u)
                    v = *(const uint4*)&enh_b[((size_t)(gy * WDIM + gx)) * C_ + h * 64 + c8 * 8];
            }
            hreg[s] = v;
        }
        __syncthreads();   // previous chunk's halo reads done
        #pragma unroll
        for (int s = 0; s < 7; ++s) {
            int seg = s * 256 + t;
            int hp = seg >> 3, c8 = seg & 7;
            if (hp < NPX_) *(uint4*)&halo[hp][c8 * 8] = hreg[s];
        }
        __syncthreads();   // halo ready; kk loop needs no further barriers

        #pragma unroll
        for (int kk = 0; kk < 9; ++kk) {
            const int kh = kk / 3, kw = kk - kh * 3;
            short8 a[8];
            #pragma unroll
            for (int q = 0; q < 8; ++q) {
                int ks = q >> 2, i2 = q & 3;
                int o = wr * 64 + i2 * 16 + lr;
                a[q] = *(const short8*)&dynk_b[(size_t)(kk * 128 + o) * 128 + h * 64 + ks * 32 + kg * 8];
            }
            #pragma unroll
            for (int ks = 0; ks < 2; ++ks) {
                short8 bfr[4];
                #pragma unroll
                for (int j = 0; j < 4; ++j) {
                    int p = wc * 64 + j * 16 + lr;
                    int py = p >> 5, pxc = p & 31;
                    bfr[j] = *(const short8*)&halo[(py + kh) * HX_ + pxc + kw][ks * 32 + kg * 8];
                }
                #pragma unroll
                for (int i2 = 0; i2 < 4; ++i2)
                    #pragma unroll
                    for (int j = 0; j < 4; ++j)
                        acc[i2][j] = __builtin_amdgcn_mfma_f32_16x16x32_bf16(a[ks * 4 + i2], bfr[j], acc[i2][j], 0, 0, 0);
            }
        }
    }

    // --- epilogue: + dyn_b, store NCHW fp32 (full 128B lines per block) ---
    #pragma unroll
    for (int i2 = 0; i2 < 4; ++i2) {
        int o_b = wr * 64 + i2 * 16 + kg * 4;
        float4 db = *(const float4*)&dyn_b[b * OUT_ + o_b];
        float dbv[4] = {db.x, db.y, db.z, db.w};
        #pragma unroll
        for (int j = 0; j < 4; ++j) {
            int p = wc * 64 + j * 16 + lr;
            int py = p >> 5, pxc = p & 31;
            int gy = gy0 + py, gx = gx0 + pxc;
            #pragma unroll
            for (int r = 0; r < 4; ++r) {
                int o = o_b + r;
                out[((size_t)(b * OUT_ + o)) * HW + gy * WDIM + gx] = acc[i2][j][r] + dbv[r];
            }
        }
    }
}

// ---------------------------------------------------------------------------
extern "C" void kernel_launch(void* const* d_in, const int* in_sizes, int n_in,
                              void* d_out, int out_size, void* d_ws, size_t ws_size,
                              hipStream_t stream)
{
    const float* ir    = (const float*)d_in[0];
    const float* vi    = (const float*)d_in[1];
    const float* kg_w1 = (const float*)d_in[2];
    const float* kg_b1 = (const float*)d_in[3];
    const float* kg_w2 = (const float*)d_in[4];
    const float* kg_b2 = (const float*)d_in[5];
    const float* bg_w1 = (const float*)d_in[6];
    const float* bg_b1 = (const float*)d_in[7];
    const float* bg_w2 = (const float*)d_in[8];
    const float* bg_b2 = (const float*)d_in[9];
    const float* en_w  = (const float*)d_in[10];
    const float* bn_g  = (const float*)d_in[11];
    const float* bn_b  = (const float*)d_in[12];
    const float* bn_m  = (const float*)d_in[13];
    const float* bn_v  = (const float*)d_in[14];
    float* out = (float*)d_out;

    char* ws = (char*)d_ws;
    float*  pooled = (float*)(ws + 0);                    // 16 KB
    float*  dyn_b  = (float*)(ws + 16384);                // 8 KB
    float*  hk     = (float*)(ws + 24576);                // 4 KB
    float*  hb     = (float*)(ws + 28672);                // 2 KB
    ushort* dynk   = (ushort*)(ws + 32768);               // 4.72 MB [b][kk][o][c]
    ushort* enh    = (ushort*)(ws + 32768 + 4718592);     // 64 MB NHWC bf16

    // bf16 copy of en_w (64 KB): use ws tail if it fits, else stash in out's
    // tail (out is only written by the final dynconv kernel -> stream-safe).
    size_t en_off = 32768 + 4718592 + 67108864;
    ushort* en_w_bf = (ws_size >= en_off + 65536)
                    ? (ushort*)(ws + en_off)
                    : (ushort*)((char*)d_out + (size_t)out_size - 65536);

    prep_kernel<<<128, 256, 0, stream>>>(en_w, en_w_bf, pooled);
    enhance_kernel<<<dim3(HDIM, B_), 256, 0, stream>>>(ir, vi, en_w_bf, bn_g, bn_b,
                                                       bn_m, bn_v, enh, pooled);
    gen_mlp1_kernel<<<6, 256, 0, stream>>>(pooled, kg_w1, kg_b1, bg_w1, bg_b1, hk, hb);
    gen_dynk_kernel<<<576, 256, 0, stream>>>(kg_w2, kg_b2, hk, hb, bg_w2, bg_b2, dynk, dyn_b);
    dynconv_kernel<<<2048, 256, 0, stream>>>(enh, dynk, dyn_b, out);
}